// Round 4
// baseline (305.079 us; speedup 1.0000x reference)
//
#include <hip/hip_runtime.h>
#include <hip/hip_bf16.h>
#include <cstdint>
#include <cstddef>

// ============================================================================
// CA3RecurrentMatrix: retrieved = query @ pinv8(A) @ A
//
// Math: with M = A^T A (C x C), retrieved = query @ h8(M),
//   h8(x) = 1 - (1 - a*x)^256 = 256*a*x - O((a*x)^2), a*x <= ~7e-7
// 2nd-order term ~9.1e-5 relative -> dropped. ||A||_F^2 = trace(M), computed
// in reduce4 from the fp32 partial sums (pre-bf16-rounding).
//
// Pipeline (4 dispatches):
//   1. prep   : At = A^T bf16 (blocks <2048) + qb = bf16(query) + wsf[4]=0
//   2. gemm_m : P[z] = At @ At^T over K-chunk z (split-K=4, fp32 partials
//               written into the OUT buffer as scratch: 4 x 16 MiB = 64 MiB
//               = out_size exactly; out is rewritten by gemm_qm afterwards).
//               m97 structure: 128^2 tile, 4 waves, single-buffer 32 KiB LDS,
//               2-barrier loop, 1024 blocks = 4 blocks/CU (16 waves/CU --
//               the occupancy regime where m97 measured 912 TF; round-2's
//               1-wave/SIMD version was the regression).
//   3. reduce4: Mb = bf16(sum_z P[z]) + trace -> wsf[4]
//   4. gemm_qm: out = c1 * (qb @ Mb^T), 256^2 tile, 8 waves, round-1's
//               4-phase schedule (measured best: 79 us / MfmaUtil 35 /
//               conflicts 0; round-2's read-ahead+sched_barrier pins
//               regressed to 87 us and are reverted).
//
// gemm_qm per K-tile t (4 phases; phase q = C-quadrant q over K=64 = 16 MFMA):
//   q0: rd A-quad0 (4xb128) + B all (8xb128, regs for whole tile); stA(t+1,h0)
//   q1: rd A-quad1;                                                stA(t+1,h1)
//   q2: rd A-quad2;                                                stB(t+2,h0)
//   q3: rd A-quad3; stB(t+2,h1); vmcnt(4)
//   each phase: s_barrier; lgkmcnt(0); setprio(1); 16 MFMA; setprio(0);
//   s_barrier.
// Hazard ledger (unchanged from round 1, measured correct):
//  - vmcnt(4)@q3 drains A(t+1) (needed at t+1 q0) and keeps B(t+2)'s 4
//    loads in flight across the barrier; tails drain to 0.
//  - stB@q2 overwrites Bs[buf] after breg was reg-captured at q0 and
//    drained by the lgkmcnt(0) before q0's MFMA (2 barriers earlier).
//  - stA@q0 overwrites As[buf^1], last read at t-1 q3 region and drained
//    before t-1 q3's MFMA (>=1 barrier before the stage issue).
//  - LDS swizzle both-sides: physical 16B slot p of row r holds logical
//    k-slot p^(r&7); staging pre-swizzles the GLOBAL source column (linear
//    LDS dest, as global_load_lds requires), reads apply the same XOR.
// ============================================================================

#define K_DIM 4096
#define C_DIM 2048
#define B_DIM 8192
#define SPLITK 4
#define KCHUNK (K_DIM / SPLITK)

typedef __bf16 bf16x8 __attribute__((ext_vector_type(8)));
typedef float f32x4 __attribute__((ext_vector_type(4)));

#define VMCNT(n) asm volatile("s_waitcnt vmcnt(" #n ")" ::: "memory")
#define LGKMCNT0 asm volatile("s_waitcnt lgkmcnt(0)" ::: "memory")
#define SBAR __builtin_amdgcn_s_barrier()

__device__ __forceinline__ void async_load16(const void* g, void* l) {
  __builtin_amdgcn_global_load_lds(
      (const __attribute__((address_space(1))) void*)g,
      (__attribute__((address_space(3))) void*)l, 16, 0, 0);
}

// --------------------------- prep: transpose + cvt + wsf zero -------------
__global__ __launch_bounds__(256) void prep_kernel(
    const float* __restrict__ A, __hip_bfloat16* __restrict__ At,
    const float* __restrict__ q, __hip_bfloat16* __restrict__ qb,
    float* __restrict__ wsf) {
  const int b = blockIdx.x;
  const int t = threadIdx.x;
  if (b < 2048) {  // ---- transpose tile: A (K,C) fp32 -> At (C,K) bf16
    __shared__ __align__(16) __hip_bfloat16 Ts[64 * 68];
    const int c0 = (b & 31) * 64;
    const int k0 = (b >> 5) * 64;
    const int c_l = t & 63;
    const int kq = t >> 6;
#pragma unroll
    for (int i = 0; i < 4; ++i) {
      int k_l = i * 16 + kq * 4;
      union { __hip_bfloat16 h[4]; uint2 u; } pk;
#pragma unroll
      for (int j = 0; j < 4; ++j)
        pk.h[j] = __float2bfloat16(A[(size_t)(k0 + k_l + j) * C_DIM + c0 + c_l]);
      *(uint2*)(Ts + c_l * 68 + k_l) = pk.u;
    }
    __syncthreads();
    const int c = t >> 2;
    const int seg = t & 3;
    const __hip_bfloat16* src = Ts + c * 68 + seg * 16;
    union { uint2 d[2]; uint4 qv; } o0, o1;
    o0.d[0] = *(const uint2*)(src + 0);
    o0.d[1] = *(const uint2*)(src + 4);
    o1.d[0] = *(const uint2*)(src + 8);
    o1.d[1] = *(const uint2*)(src + 12);
    __hip_bfloat16* dst = At + (size_t)(c0 + c) * K_DIM + k0 + seg * 16;
    *(uint4*)(dst + 0) = o0.qv;
    *(uint4*)(dst + 8) = o1.qv;
  } else {  // ---- cvt query -> qb (1024 blocks, grid-stride)
    if (b == 2048 && t == 0) wsf[4] = 0.0f;
    const int n4 = B_DIM * C_DIM / 4;
    int tid = (b - 2048) * 256 + t;
    for (int i = tid; i < n4; i += 1024 * 256) {
      float4 v = ((const float4*)q)[i];
      __hip_bfloat16 o[4] = {__float2bfloat16(v.x), __float2bfloat16(v.y),
                             __float2bfloat16(v.z), __float2bfloat16(v.w)};
      *(uint2*)(qb + 4 * (size_t)i) = *(const uint2*)o;
    }
  }
}

// --------------------------- gemm_m: P[z] = At @ At^T (K-chunk z) ---------
// m97 structure: 128x128 tile, 4 waves (2x2, wave tile 64x64), BK=64,
// single-buffered LDS (32 KiB), 2-barrier loop, fp32 partial out.
__global__ __launch_bounds__(256, 4) void gemm_m(
    const __hip_bfloat16* __restrict__ At, float* __restrict__ P) {
  constexpr int BK = 64;
  constexpr int NT = KCHUNK / BK;  // 16
  __shared__ __align__(16) __hip_bfloat16 As[128 * BK];  // 16 KiB
  __shared__ __align__(16) __hip_bfloat16 Bs[128 * BK];  // 16 KiB
  const int tid = threadIdx.x;
  const int wave = tid >> 6, lane = tid & 63;
  const int tile_m = blockIdx.y * 128, tile_n = blockIdx.x * 128;
  const int kstart = blockIdx.z * KCHUNK;
  const int wm = (wave >> 1) * 64, wn = (wave & 1) * 64;
  const int lr = lane >> 3, lcl = (lane & 7) ^ lr;
  const __hip_bfloat16* aB =
      At + (size_t)(tile_m + wave * 32 + lr) * K_DIM + kstart + lcl * 8;
  const __hip_bfloat16* bB =
      At + (size_t)(tile_n + wave * 32 + lr) * K_DIM + kstart + lcl * 8;
  const int l15 = lane & 15, lg = lane >> 4, l7 = lane & 7;
  f32x4 acc[4][4] = {};

  for (int t = 0; t < NT; ++t) {
#pragma unroll
    for (int c = 0; c < 4; ++c) {
      async_load16(aB + (size_t)(c * 8) * K_DIM + (size_t)t * BK,
                   &As[(wave * 32 + c * 8) * BK]);
      async_load16(bB + (size_t)(c * 8) * K_DIM + (size_t)t * BK,
                   &Bs[(wave * 32 + c * 8) * BK]);
    }
    __syncthreads();  // drains vmcnt (global_load_lds) + aligns waves
#pragma unroll
    for (int kh = 0; kh < 2; ++kh) {
      bf16x8 a[4], bb[4];
#pragma unroll
      for (int f = 0; f < 4; ++f) {
        a[f]  = *(const bf16x8*)&As[(wm + f * 16 + l15) * BK +
                                    (((kh * 4 + lg) ^ l7) * 8)];
        bb[f] = *(const bf16x8*)&Bs[(wn + f * 16 + l15) * BK +
                                    (((kh * 4 + lg) ^ l7) * 8)];
      }
      __builtin_amdgcn_s_setprio(1);
#pragma unroll
      for (int f = 0; f < 4; ++f)
#pragma unroll
        for (int j = 0; j < 4; ++j)
          acc[f][j] = __builtin_amdgcn_mfma_f32_16x16x32_bf16(
              a[f], bb[j], acc[f][j], 0, 0, 0);
      __builtin_amdgcn_s_setprio(0);
    }
    __syncthreads();  // protect As/Bs before next-iter overwrite
  }

  // epilogue: fp32 partial. C/D (16x16): col = lane&15, row = (lane>>4)*4+reg
  float* Pz = P + (size_t)blockIdx.z * C_DIM * C_DIM;
#pragma unroll
  for (int f = 0; f < 4; ++f) {
    const int gm = tile_m + wm + f * 16 + lg * 4;
#pragma unroll
    for (int j = 0; j < 4; ++j) {
      const int gn = tile_n + wn + j * 16 + l15;
#pragma unroll
      for (int r = 0; r < 4; ++r)
        Pz[(size_t)(gm + r) * C_DIM + gn] = acc[f][j][r];
    }
  }
}

// ------------------- reduce4: Mb = bf16(sum P[z]) + trace -----------------
__global__ __launch_bounds__(256) void reduce4_kernel(
    const float* __restrict__ P, __hip_bfloat16* __restrict__ Mb,
    float* __restrict__ wsf) {
  const size_t CC = (size_t)C_DIM * C_DIM;
  const int n4 = (int)(CC / 4);
  int tid = blockIdx.x * blockDim.x + threadIdx.x;
  int stride = gridDim.x * blockDim.x;
  float tsum = 0.0f;
  for (int i = tid; i < n4; i += stride) {
    float4 a = ((const float4*)P)[i];
#pragma unroll
    for (int z = 1; z < SPLITK; ++z) {
      float4 b = *(const float4*)(P + z * CC + (size_t)i * 4);
      a.x += b.x; a.y += b.y; a.z += b.z; a.w += b.w;
    }
    __hip_bfloat16 o[4] = {__float2bfloat16(a.x), __float2bfloat16(a.y),
                           __float2bfloat16(a.z), __float2bfloat16(a.w)};
    *(uint2*)(Mb + 4 * (size_t)i) = *(const uint2*)o;
    const float av[4] = {a.x, a.y, a.z, a.w};
#pragma unroll
    for (int j = 0; j < 4; ++j) {
      int e = 4 * i + j;
      if (e % (C_DIM + 1) == 0) tsum += av[j];  // diagonal element
    }
  }
  if (tsum != 0.0f) atomicAdd(wsf + 4, tsum);
}

// --------------------------- gemm_qm: out = c1 * qb @ Mb^T ----------------
// Round-1 4-phase schedule (measured best). 256x256 tile, 8 waves (2Mx4N),
// wave tile 128x64, BK=64, double-buffered 128 KiB LDS.
__global__ __launch_bounds__(512, 2) void gemm_qm(
    const __hip_bfloat16* __restrict__ Ab, const __hip_bfloat16* __restrict__ Bb,
    float* __restrict__ Fp, const float* __restrict__ ls,
    const float* __restrict__ wsf) {
  constexpr int BK = 64;
  constexpr int NT = C_DIM / BK;  // 32
  __shared__ __align__(16) __hip_bfloat16 As[2][256 * BK];
  __shared__ __align__(16) __hip_bfloat16 Bs[2][256 * BK];
  const int tid = threadIdx.x;
  const int wave = tid >> 6, lane = tid & 63;
  const int tile_m = blockIdx.y * 256, tile_n = blockIdx.x * 256;
  const int wm = (wave >> 2) * 128, wn = (wave & 3) * 64;
  const int lr = lane >> 3, lcl = (lane & 7) ^ lr;
  const __hip_bfloat16* aBase =
      Ab + (size_t)(tile_m + wave * 16 + lr) * C_DIM + lcl * 8;
  const __hip_bfloat16* bBase =
      Bb + (size_t)(tile_n + wave * 16 + lr) * C_DIM + lcl * 8;
  const int l15 = lane & 15, lg = lane >> 4, l7 = lane & 7;

  auto stA = [&](int buf, int h, int t) {
    const __hip_bfloat16* s = aBase + (size_t)(h * 128) * C_DIM + (size_t)t * BK;
    __hip_bfloat16* d = &As[buf][(h * 128 + wave * 16) * BK];
    async_load16(s, d);
    async_load16(s + (size_t)8 * C_DIM, d + 8 * BK);
  };
  auto stB = [&](int buf, int h, int t) {
    const __hip_bfloat16* s = bBase + (size_t)(h * 128) * C_DIM + (size_t)t * BK;
    __hip_bfloat16* d = &Bs[buf][(h * 128 + wave * 16) * BK];
    async_load16(s, d);
    async_load16(s + (size_t)8 * C_DIM, d + 8 * BK);
  };

  f32x4 acc[8][4] = {};

  // prologue: A(0), B(0) must land; B(1)'s 4 loads stay in flight
  stA(0, 0, 0); stA(0, 1, 0);
  stB(0, 0, 0); stB(0, 1, 0);
  stB(1, 0, 1); stB(1, 1, 1);
  VMCNT(4);
  SBAR;

  for (int t = 0; t < NT; ++t) {
    const int buf = t & 1;
    bf16x8 breg[4][2];
#pragma unroll
    for (int q = 0; q < 4; ++q) {
      // ---- ds reads for this phase (same-tile consume) ----
      bf16x8 af[2][2];
#pragma unroll
      for (int f = 0; f < 2; ++f)
#pragma unroll
        for (int s = 0; s < 2; ++s)
          af[f][s] = *(const bf16x8*)&As[buf][(wm + q * 32 + f * 16 + l15) * BK +
                                             ((((s << 2) | lg) ^ l7) << 3)];
      if (q == 0) {
#pragma unroll
        for (int j = 0; j < 4; ++j)
#pragma unroll
          for (int s = 0; s < 2; ++s)
            breg[j][s] = *(const bf16x8*)&Bs[buf][(wn + j * 16 + l15) * BK +
                                                 ((((s << 2) | lg) ^ l7) << 3)];
      }
      // ---- stage one half-tile (schedule per header) ----
      if (q == 0 && t + 1 < NT) stA(buf ^ 1, 0, t + 1);
      if (q == 1 && t + 1 < NT) stA(buf ^ 1, 1, t + 1);
      if (q == 2 && t + 2 < NT) stB(buf, 0, t + 2);
      if (q == 3) {
        if (t + 2 < NT) {
          stB(buf, 1, t + 2);
          VMCNT(4);
        } else {
          VMCNT(0);
        }
      }
      SBAR;
      LGKMCNT0;
      __builtin_amdgcn_s_setprio(1);
#pragma unroll
      for (int s = 0; s < 2; ++s)
#pragma unroll
        for (int f = 0; f < 2; ++f)
#pragma unroll
          for (int j = 0; j < 4; ++j)
            acc[q * 2 + f][j] = __builtin_amdgcn_mfma_f32_16x16x32_bf16(
                af[f][s], breg[j][s], acc[q * 2 + f][j], 0, 0, 0);
      __builtin_amdgcn_s_setprio(0);
      SBAR;
    }
  }

  // epilogue: C/D (16x16): col = lane&15, row = (lane>>4)*4 + reg
  const float c1 = 256.0f * fminf(expf(ls[0]), 5e-4f) / (wsf[4] + 1e-8f);
#pragma unroll
  for (int m = 0; m < 8; ++m) {
    const int gm = tile_m + wm + m * 16 + lg * 4;
#pragma unroll
    for (int j = 0; j < 4; ++j) {
      const int gn = tile_n + wn + j * 16 + l15;
#pragma unroll
      for (int r = 0; r < 4; ++r)
        Fp[(size_t)(gm + r) * C_DIM + gn] = c1 * acc[m][j][r];
    }
  }
}

// ------------------------------------------------------------- launch -----
extern "C" void kernel_launch(void* const* d_in, const int* in_sizes, int n_in,
                              void* d_out, int out_size, void* d_ws, size_t ws_size,
                              hipStream_t stream) {
  const float* query = (const float*)d_in[0];
  const float* A = (const float*)d_in[1];
  const float* ls = (const float*)d_in[2];
  float* out = (float*)d_out;

  char* ws = (char*)d_ws;
  float* wsf = (float*)ws;
  size_t off = 256;
  __hip_bfloat16* At = (__hip_bfloat16*)(ws + off);
  off += (size_t)C_DIM * K_DIM * 2;  // 16 MiB
  __hip_bfloat16* qb = (__hip_bfloat16*)(ws + off);
  off += (size_t)B_DIM * C_DIM * 2;  // 32 MiB
  __hip_bfloat16* Mb = (__hip_bfloat16*)(ws + off);  // 8 MiB

  // split-K fp32 partials live in the OUT buffer (4 x 16 MiB = 64 MiB =
  // out_size exactly); gemm_qm overwrites out afterwards.
  float* P = out;

  // 1) At = A^T bf16 ; qb = bf16(query) ; wsf[4] = 0
  prep_kernel<<<3072, 256, 0, stream>>>(A, At, query, qb, wsf);
  // 2) P[z] = At @ At^T over K-chunk z  (1024 blocks = 4 blocks/CU)
  gemm_m<<<dim3(C_DIM / 128, C_DIM / 128, SPLITK), 256, 0, stream>>>(At, P);
  // 3) Mb = bf16(sum_z P[z]) + trace -> wsf[4]
  reduce4_kernel<<<1024, 256, 0, stream>>>(P, Mb, wsf);
  // 4) out = c1 * qb @ Mb^T  (Mb symmetric)
  gemm_qm<<<dim3(C_DIM / 256, B_DIM / 256), 512, 0, stream>>>(qb, Mb, out, ls, wsf);
}

// Round 5
// 275.304 us; speedup vs baseline: 1.1082x; 1.1082x over previous
//
#include <hip/hip_runtime.h>
#include <hip/hip_bf16.h>
#include <cstdint>
#include <cstddef>

// ============================================================================
// CA3RecurrentMatrix: retrieved = query @ pinv8(A) @ A
//
// Math: with M = A^T A (C x C), retrieved = query @ h8(M),
//   h8(x) = 1 - (1 - a*x)^256 = 256*a*x - O((a*x)^2), a*x <= ~7e-7
// 2nd-order term ~9.1e-5 relative -> dropped. ||A||_F^2 = trace(M), computed
// in reduce4 from the fp32 partial sums (pre-bf16-rounding).
//
// Pipeline (4 dispatches):
//   1. prep   : At = A^T bf16 (blocks <2048) + qb = bf16(query) + wsf[4]=0
//   2. gemm_m : P[z] = At @ At^T over K-chunk z (split-K=4, fp32 partials in
//               the OUT buffer as scratch: 4 x 16 MiB = 64 MiB = out_size;
//               out is rewritten by gemm_qm afterwards). m97 structure,
//               1024 blocks = 4 blocks/CU. NEW: XCD-aware swizzle -- each
//               XCD owns half a z-slice (all 16 tm x 8 tn); union of panel
//               reads = the whole 4 MiB At z-slice = exactly one XCD L2.
//   3. reduce4: Mb = bf16(sum_z P[z]) + trace -> wsf[4]
//   4. gemm_qm: out = c1 * (qb @ Mb^T), 256^2 tile, 8 waves, round-1's
//               4-phase schedule. NEW: XCD-aware swizzle -- each XCD owns
//               4 tm x all 8 tn (fetch/XCD = 4 MiB qb + 8 MiB Mb).
//
// gemm_qm per K-tile t (4 phases; phase q = C-quadrant q over K=64 = 16 MFMA):
//   q0: rd A-quad0 (4xb128) + B all (8xb128, regs for whole tile); stA(t+1,h0)
//   q1: rd A-quad1;                                                stA(t+1,h1)
//   q2: rd A-quad2;                                                stB(t+2,h0)
//   q3: rd A-quad3; stB(t+2,h1); vmcnt(4)
//   each phase: s_barrier; lgkmcnt(0); setprio(1); 16 MFMA; setprio(0);
//   s_barrier.
// Hazard ledger (measured correct in rounds 1/4):
//  - vmcnt(4)@q3 drains A(t+1) (needed at t+1 q0) and keeps B(t+2)'s 4
//    loads in flight across the barrier; tails drain to 0.
//  - stB@q2 overwrites Bs[buf] after breg was reg-captured at q0 and
//    drained by the lgkmcnt(0) before q0's MFMA (2 barriers earlier).
//  - stA@q0 overwrites As[buf^1], last read at t-1 q3 region and drained
//    before t-1 q3's MFMA (>=1 barrier before the stage issue).
//  - LDS swizzle both-sides: physical 16B slot p of row r holds logical
//    k-slot p^(r&7); staging pre-swizzles the GLOBAL source column (linear
//    LDS dest, as global_load_lds requires), reads apply the same XOR.
// ============================================================================

#define K_DIM 4096
#define C_DIM 2048
#define B_DIM 8192
#define SPLITK 4
#define KCHUNK (K_DIM / SPLITK)

typedef __bf16 bf16x8 __attribute__((ext_vector_type(8)));
typedef float f32x4 __attribute__((ext_vector_type(4)));

#define VMCNT(n) asm volatile("s_waitcnt vmcnt(" #n ")" ::: "memory")
#define LGKMCNT0 asm volatile("s_waitcnt lgkmcnt(0)" ::: "memory")
#define SBAR __builtin_amdgcn_s_barrier()

__device__ __forceinline__ void async_load16(const void* g, void* l) {
  __builtin_amdgcn_global_load_lds(
      (const __attribute__((address_space(1))) void*)g,
      (__attribute__((address_space(3))) void*)l, 16, 0, 0);
}

// --------------------------- prep: transpose + cvt + wsf zero -------------
__global__ __launch_bounds__(256) void prep_kernel(
    const float* __restrict__ A, __hip_bfloat16* __restrict__ At,
    const float* __restrict__ q, __hip_bfloat16* __restrict__ qb,
    float* __restrict__ wsf) {
  const int b = blockIdx.x;
  const int t = threadIdx.x;
  if (b < 2048) {  // ---- transpose tile: A (K,C) fp32 -> At (C,K) bf16
    __shared__ __align__(16) __hip_bfloat16 Ts[64 * 68];
    const int c0 = (b & 31) * 64;
    const int k0 = (b >> 5) * 64;
    const int c_l = t & 63;
    const int kq = t >> 6;
#pragma unroll
    for (int i = 0; i < 4; ++i) {
      int k_l = i * 16 + kq * 4;
      union { __hip_bfloat16 h[4]; uint2 u; } pk;
#pragma unroll
      for (int j = 0; j < 4; ++j)
        pk.h[j] = __float2bfloat16(A[(size_t)(k0 + k_l + j) * C_DIM + c0 + c_l]);
      *(uint2*)(Ts + c_l * 68 + k_l) = pk.u;
    }
    __syncthreads();
    const int c = t >> 2;
    const int seg = t & 3;
    const __hip_bfloat16* src = Ts + c * 68 + seg * 16;
    union { uint2 d[2]; uint4 qv; } o0, o1;
    o0.d[0] = *(const uint2*)(src + 0);
    o0.d[1] = *(const uint2*)(src + 4);
    o1.d[0] = *(const uint2*)(src + 8);
    o1.d[1] = *(const uint2*)(src + 12);
    __hip_bfloat16* dst = At + (size_t)(c0 + c) * K_DIM + k0 + seg * 16;
    *(uint4*)(dst + 0) = o0.qv;
    *(uint4*)(dst + 8) = o1.qv;
  } else {  // ---- cvt query -> qb (1024 blocks, grid-stride)
    if (b == 2048 && t == 0) wsf[4] = 0.0f;
    const int n4 = B_DIM * C_DIM / 4;
    int tid = (b - 2048) * 256 + t;
    for (int i = tid; i < n4; i += 1024 * 256) {
      float4 v = ((const float4*)q)[i];
      __hip_bfloat16 o[4] = {__float2bfloat16(v.x), __float2bfloat16(v.y),
                             __float2bfloat16(v.z), __float2bfloat16(v.w)};
      *(uint2*)(qb + 4 * (size_t)i) = *(const uint2*)o;
    }
  }
}

// --------------------------- gemm_m: P[z] = At @ At^T (K-chunk z) ---------
// m97 structure: 128x128 tile, 4 waves (2x2, wave tile 64x64), BK=64,
// single-buffered LDS (32 KiB), 2-barrier loop, fp32 partial out.
// 1-D grid 1024; XCD swizzle: sw = (bid&7)*128 + (bid>>3); XCD i owns
// sw in [128i,128i+128) = {z = i>>1, tn in [ (i&1)*8, +8 ), all tm} -->
// union of A/B panels = entire 4 MiB At z-slice (fits one XCD L2).
__global__ __launch_bounds__(256, 4) void gemm_m(
    const __hip_bfloat16* __restrict__ At, float* __restrict__ P) {
  constexpr int BK = 64;
  constexpr int NT = KCHUNK / BK;  // 16
  __shared__ __align__(16) __hip_bfloat16 As[128 * BK];  // 16 KiB
  __shared__ __align__(16) __hip_bfloat16 Bs[128 * BK];  // 16 KiB
  const int bid = blockIdx.x;
  const int sw = (bid & 7) * 128 + (bid >> 3);
  const int z = sw >> 8;            // [0,4)
  const int r = sw & 255;
  const int tn_i = r >> 4;          // [0,16)
  const int tm_i = r & 15;          // [0,16)
  const int tid = threadIdx.x;
  const int wave = tid >> 6, lane = tid & 63;
  const int tile_m = tm_i * 128, tile_n = tn_i * 128;
  const int kstart = z * KCHUNK;
  const int wm = (wave >> 1) * 64, wn = (wave & 1) * 64;
  const int lr = lane >> 3, lcl = (lane & 7) ^ lr;
  const __hip_bfloat16* aB =
      At + (size_t)(tile_m + wave * 32 + lr) * K_DIM + kstart + lcl * 8;
  const __hip_bfloat16* bB =
      At + (size_t)(tile_n + wave * 32 + lr) * K_DIM + kstart + lcl * 8;
  const int l15 = lane & 15, lg = lane >> 4, l7 = lane & 7;
  f32x4 acc[4][4] = {};

  for (int t = 0; t < NT; ++t) {
#pragma unroll
    for (int c = 0; c < 4; ++c) {
      async_load16(aB + (size_t)(c * 8) * K_DIM + (size_t)t * BK,
                   &As[(wave * 32 + c * 8) * BK]);
      async_load16(bB + (size_t)(c * 8) * K_DIM + (size_t)t * BK,
                   &Bs[(wave * 32 + c * 8) * BK]);
    }
    __syncthreads();  // drains vmcnt (global_load_lds) + aligns waves
#pragma unroll
    for (int kh = 0; kh < 2; ++kh) {
      bf16x8 a[4], bb[4];
#pragma unroll
      for (int f = 0; f < 4; ++f) {
        a[f]  = *(const bf16x8*)&As[(wm + f * 16 + l15) * BK +
                                    (((kh * 4 + lg) ^ l7) * 8)];
        bb[f] = *(const bf16x8*)&Bs[(wn + f * 16 + l15) * BK +
                                    (((kh * 4 + lg) ^ l7) * 8)];
      }
      __builtin_amdgcn_s_setprio(1);
#pragma unroll
      for (int f = 0; f < 4; ++f)
#pragma unroll
        for (int j = 0; j < 4; ++j)
          acc[f][j] = __builtin_amdgcn_mfma_f32_16x16x32_bf16(
              a[f], bb[j], acc[f][j], 0, 0, 0);
      __builtin_amdgcn_s_setprio(0);
    }
    __syncthreads();  // protect As/Bs before next-iter overwrite
  }

  // epilogue: fp32 partial. C/D (16x16): col = lane&15, row = (lane>>4)*4+reg
  float* Pz = P + (size_t)z * C_DIM * C_DIM;
#pragma unroll
  for (int f = 0; f < 4; ++f) {
    const int gm = tile_m + wm + f * 16 + lg * 4;
#pragma unroll
    for (int j = 0; j < 4; ++j) {
      const int gn = tile_n + wn + j * 16 + l15;
#pragma unroll
      for (int r2 = 0; r2 < 4; ++r2)
        Pz[(size_t)(gm + r2) * C_DIM + gn] = acc[f][j][r2];
    }
  }
}

// ------------------- reduce4: Mb = bf16(sum P[z]) + trace -----------------
__global__ __launch_bounds__(256) void reduce4_kernel(
    const float* __restrict__ P, __hip_bfloat16* __restrict__ Mb,
    float* __restrict__ wsf) {
  const size_t CC = (size_t)C_DIM * C_DIM;
  const int n4 = (int)(CC / 4);
  int tid = blockIdx.x * blockDim.x + threadIdx.x;
  int stride = gridDim.x * blockDim.x;
  float tsum = 0.0f;
  bool hit = false;
  for (int i = tid; i < n4; i += stride) {
    float4 a = ((const float4*)P)[i];
#pragma unroll
    for (int z = 1; z < SPLITK; ++z) {
      float4 b = *(const float4*)(P + z * CC + (size_t)i * 4);
      a.x += b.x; a.y += b.y; a.z += b.z; a.w += b.w;
    }
    __hip_bfloat16 o[4] = {__float2bfloat16(a.x), __float2bfloat16(a.y),
                           __float2bfloat16(a.z), __float2bfloat16(a.w)};
    *(uint2*)(Mb + 4 * (size_t)i) = *(const uint2*)o;
    // diag of row g sits at flat index g*(C_DIM+1); this thread's 4-elem
    // window [4i,4i+4) contains at most one.
    const int e0 = 4 * i;
    const int g = e0 >> 11;                  // row of e0
    const int d = g * (C_DIM + 1);
    if (d >= e0 && d < e0 + 4) {
      const float av[4] = {a.x, a.y, a.z, a.w};
      tsum += av[d - e0];
      hit = true;
    }
  }
  if (hit) atomicAdd(wsf + 4, tsum);
}

// --------------------------- gemm_qm: out = c1 * qb @ Mb^T ----------------
// Round-1 4-phase schedule (measured best). 256x256 tile, 8 waves (2Mx4N),
// wave tile 128x64, BK=64, double-buffered 128 KiB LDS.
// 1-D grid 256; XCD swizzle: sw = (bid&7)*32 + (bid>>3); XCD i owns
// sw in [32i,32i+32) = {tm in [4i,4i+4), all 8 tn} -> fetch/XCD =
// 4 MiB qb panel + 8 MiB Mb.
__global__ __launch_bounds__(512, 2) void gemm_qm(
    const __hip_bfloat16* __restrict__ Ab, const __hip_bfloat16* __restrict__ Bb,
    float* __restrict__ Fp, const float* __restrict__ ls,
    const float* __restrict__ wsf) {
  constexpr int BK = 64;
  constexpr int NT = C_DIM / BK;  // 32
  __shared__ __align__(16) __hip_bfloat16 As[2][256 * BK];
  __shared__ __align__(16) __hip_bfloat16 Bs[2][256 * BK];
  const int bid = blockIdx.x;
  const int sw = (bid & 7) * 32 + (bid >> 3);
  const int tn_i = sw & 7;    // [0,8)
  const int tm_i = sw >> 3;   // [0,32)
  const int tid = threadIdx.x;
  const int wave = tid >> 6, lane = tid & 63;
  const int tile_m = tm_i * 256, tile_n = tn_i * 256;
  const int wm = (wave >> 2) * 128, wn = (wave & 3) * 64;
  const int lr = lane >> 3, lcl = (lane & 7) ^ lr;
  const __hip_bfloat16* aBase =
      Ab + (size_t)(tile_m + wave * 16 + lr) * C_DIM + lcl * 8;
  const __hip_bfloat16* bBase =
      Bb + (size_t)(tile_n + wave * 16 + lr) * C_DIM + lcl * 8;
  const int l15 = lane & 15, lg = lane >> 4, l7 = lane & 7;

  auto stA = [&](int buf, int h, int t) {
    const __hip_bfloat16* s = aBase + (size_t)(h * 128) * C_DIM + (size_t)t * BK;
    __hip_bfloat16* d = &As[buf][(h * 128 + wave * 16) * BK];
    async_load16(s, d);
    async_load16(s + (size_t)8 * C_DIM, d + 8 * BK);
  };
  auto stB = [&](int buf, int h, int t) {
    const __hip_bfloat16* s = bBase + (size_t)(h * 128) * C_DIM + (size_t)t * BK;
    __hip_bfloat16* d = &Bs[buf][(h * 128 + wave * 16) * BK];
    async_load16(s, d);
    async_load16(s + (size_t)8 * C_DIM, d + 8 * BK);
  };

  f32x4 acc[8][4] = {};

  // prologue: A(0), B(0) must land; B(1)'s 4 loads stay in flight
  stA(0, 0, 0); stA(0, 1, 0);
  stB(0, 0, 0); stB(0, 1, 0);
  stB(1, 0, 1); stB(1, 1, 1);
  VMCNT(4);
  SBAR;

  for (int t = 0; t < NT; ++t) {
    const int buf = t & 1;
    bf16x8 breg[4][2];
#pragma unroll
    for (int q = 0; q < 4; ++q) {
      // ---- ds reads for this phase (same-tile consume) ----
      bf16x8 af[2][2];
#pragma unroll
      for (int f = 0; f < 2; ++f)
#pragma unroll
        for (int s = 0; s < 2; ++s)
          af[f][s] = *(const bf16x8*)&As[buf][(wm + q * 32 + f * 16 + l15) * BK +
                                             ((((s << 2) | lg) ^ l7) << 3)];
      if (q == 0) {
#pragma unroll
        for (int j = 0; j < 4; ++j)
#pragma unroll
          for (int s = 0; s < 2; ++s)
            breg[j][s] = *(const bf16x8*)&Bs[buf][(wn + j * 16 + l15) * BK +
                                                 ((((s << 2) | lg) ^ l7) << 3)];
      }
      // ---- stage one half-tile (schedule per header) ----
      if (q == 0 && t + 1 < NT) stA(buf ^ 1, 0, t + 1);
      if (q == 1 && t + 1 < NT) stA(buf ^ 1, 1, t + 1);
      if (q == 2 && t + 2 < NT) stB(buf, 0, t + 2);
      if (q == 3) {
        if (t + 2 < NT) {
          stB(buf, 1, t + 2);
          VMCNT(4);
        } else {
          VMCNT(0);
        }
      }
      SBAR;
      LGKMCNT0;
      __builtin_amdgcn_s_setprio(1);
#pragma unroll
      for (int s = 0; s < 2; ++s)
#pragma unroll
        for (int f = 0; f < 2; ++f)
#pragma unroll
          for (int j = 0; j < 4; ++j)
            acc[q * 2 + f][j] = __builtin_amdgcn_mfma_f32_16x16x32_bf16(
                af[f][s], breg[j][s], acc[q * 2 + f][j], 0, 0, 0);
      __builtin_amdgcn_s_setprio(0);
      SBAR;
    }
  }

  // epilogue: C/D (16x16): col = lane&15, row = (lane>>4)*4 + reg
  const float c1 = 256.0f * fminf(expf(ls[0]), 5e-4f) / (wsf[4] + 1e-8f);
#pragma unroll
  for (int m = 0; m < 8; ++m) {
    const int gm = tile_m + wm + m * 16 + lg * 4;
#pragma unroll
    for (int j = 0; j < 4; ++j) {
      const int gn = tile_n + wn + j * 16 + l15;
#pragma unroll
      for (int r = 0; r < 4; ++r)
        Fp[(size_t)(gm + r) * C_DIM + gn] = c1 * acc[m][j][r];
    }
  }
}

// ------------------------------------------------------------- launch -----
extern "C" void kernel_launch(void* const* d_in, const int* in_sizes, int n_in,
                              void* d_out, int out_size, void* d_ws, size_t ws_size,
                              hipStream_t stream) {
  const float* query = (const float*)d_in[0];
  const float* A = (const float*)d_in[1];
  const float* ls = (const float*)d_in[2];
  float* out = (float*)d_out;

  char* ws = (char*)d_ws;
  float* wsf = (float*)ws;
  size_t off = 256;
  __hip_bfloat16* At = (__hip_bfloat16*)(ws + off);
  off += (size_t)C_DIM * K_DIM * 2;  // 16 MiB
  __hip_bfloat16* qb = (__hip_bfloat16*)(ws + off);
  off += (size_t)B_DIM * C_DIM * 2;  // 32 MiB
  __hip_bfloat16* Mb = (__hip_bfloat16*)(ws + off);  // 8 MiB

  // split-K fp32 partials live in the OUT buffer (4 x 16 MiB = 64 MiB =
  // out_size exactly); gemm_qm overwrites out afterwards.
  float* P = out;

  // 1) At = A^T bf16 ; qb = bf16(query) ; wsf[4] = 0
  prep_kernel<<<3072, 256, 0, stream>>>(A, At, query, qb, wsf);
  // 2) P[z] = At @ At^T over K-chunk z  (1024 blocks = 4/CU, XCD-chunked)
  gemm_m<<<1024, 256, 0, stream>>>(At, P);
  // 3) Mb = bf16(sum_z P[z]) + trace -> wsf[4]
  reduce4_kernel<<<1024, 256, 0, stream>>>(P, Mb, wsf);
  // 4) out = c1 * qb @ Mb^T  (Mb symmetric; 256 blocks, XCD-chunked)
  gemm_qm<<<256, 512, 0, stream>>>(qb, Mb, out, ls, wsf);
}

// Round 6
// 270.477 us; speedup vs baseline: 1.1279x; 1.0178x over previous
//
#include <hip/hip_runtime.h>
#include <hip/hip_bf16.h>
#include <cstdint>
#include <cstddef>
#include <math.h>

// ============================================================================
// CA3RecurrentMatrix: retrieved = query @ pinv8(A) @ A
//
// Math: with M = A^T A (C x C), retrieved = query @ h8(M),
//   h8(x) = 1 - (1 - a*x)^256 = 256*a*x - O((a*x)^2), a*x <= ~7e-7.
// ||A||_F^2 = trace(M) from fp32 partials in reduce4.
//
// Pipeline (4 dispatches):
//   1. prep   : At = A^T bf16 + qb = bf16(query) + wsf[4]=0
//   2. gemm_m : TRIANGLE-ONLY (tm>=tn, 136/256 tiles, mirror-write float4)
//               P[z] = At @ At^T over K-chunk z (split-K=4, fp32 partials in
//               the OUT buffer: 4 x 16 MiB = out_size). Grid 544 = 8x68
//               XCD-chunked; ~2.1 blocks/CU.
//   3. reduce4: Mb = bf16(sum_z P[z]) + trace -> wsf[4]
//   4. gemm_qm: out = c1 * (qb @ Mb^T), 256^2 tile, 8 waves, SINGLE-BARRIER
//               4-phase schedule (this round's experiment).
//
// gemm_qm phases (p = (s,mh); s = k-half of BK=64, mh = 64-row half of the
// wave's 128 rows). Phase = [region: ds_reads | s_barrier | post: stages,
// lgkmcnt(0), 16 MFMA]. Reads for phase p are issued BEFORE bar(p), so they
// drain while other waves still run phase p-1's MFMA -- the LDS pipe and
// matrix pipe overlap instead of alternating (the 2-barrier structure
// measured 27-35% MfmaUtil across 4 variants = serialized ceiling).
//   p0 region: af(mh0,s0)x4 + bfr(s0)x4    | post: stA(t+1,h0); mm(mh0)
//   p1 region: af(mh1,s0)x4                | post: stA(t+1,h1); mm(mh1)
//   p2 region: af(mh0,s1)x4 + bfr(s1)x4    | post:              mm(mh0)
//   p3 region: af(mh1,s1)x4; vmcnt(0)      | post: stB(t+2,h0+h1); mm(mh1)
// Hazard ledger (single-barrier, re-derived):
//  - stA@p0-post writes As[buf^1]; last reads of As[buf^1] are tile t-1's
//    regions, drained per-wave by lgkm0@p3-post(t-1) which precedes
//    region(p0,t) in program order -> bar(p0,t) gives cross-wave order.
//  - stB@p3-post writes Bs[buf] (parity of t+2 == t); last reads of Bs[buf]
//    are bfr@p0 (drained lgkm0@p0-post) and bfr@p2 (drained lgkm0@p2-post);
//    bar(p3,t) follows p2-post in program order for all waves.
//  - vmcnt(0)@region(p3,t) drains A(t+1) (issued p0/p1-post, ~2 phases old)
//    and B(t+1) (issued p3-post(t-1), ~4 phases old) -- both cheap by then;
//    bar(p3,t) separates the drain from tile t+1's region reads. stB(t+2)
//    is issued AFTER the vmcnt -> stays in flight 4 phases.
//  - LDS swizzle both-sides: physical 16B slot p of row r holds logical
//    k-slot p^(r&7); staging pre-swizzles the GLOBAL source column (linear
//    LDS dest, as global_load_lds requires), reads apply the same XOR.
//  - XCD swizzle kept (round 5: FETCH 135->49 MB measured).
// ============================================================================

#define K_DIM 4096
#define C_DIM 2048
#define B_DIM 8192
#define SPLITK 4
#define KCHUNK (K_DIM / SPLITK)

typedef __bf16 bf16x8 __attribute__((ext_vector_type(8)));
typedef float f32x4 __attribute__((ext_vector_type(4)));

#define VMCNT(n) asm volatile("s_waitcnt vmcnt(" #n ")" ::: "memory")
#define LGKMCNT0 asm volatile("s_waitcnt lgkmcnt(0)" ::: "memory")
#define SBAR __builtin_amdgcn_s_barrier()

__device__ __forceinline__ void async_load16(const void* g, void* l) {
  __builtin_amdgcn_global_load_lds(
      (const __attribute__((address_space(1))) void*)g,
      (__attribute__((address_space(3))) void*)l, 16, 0, 0);
}

// --------------------------- prep: transpose + cvt + wsf zero -------------
__global__ __launch_bounds__(256) void prep_kernel(
    const float* __restrict__ A, __hip_bfloat16* __restrict__ At,
    const float* __restrict__ q, __hip_bfloat16* __restrict__ qb,
    float* __restrict__ wsf) {
  const int b = blockIdx.x;
  const int t = threadIdx.x;
  if (b < 2048) {  // ---- transpose tile: A (K,C) fp32 -> At (C,K) bf16
    __shared__ __align__(16) __hip_bfloat16 Ts[64 * 68];
    const int c0 = (b & 31) * 64;
    const int k0 = (b >> 5) * 64;
    const int c_l = t & 63;
    const int kq = t >> 6;
#pragma unroll
    for (int i = 0; i < 4; ++i) {
      int k_l = i * 16 + kq * 4;
      union { __hip_bfloat16 h[4]; uint2 u; } pk;
#pragma unroll
      for (int j = 0; j < 4; ++j)
        pk.h[j] = __float2bfloat16(A[(size_t)(k0 + k_l + j) * C_DIM + c0 + c_l]);
      *(uint2*)(Ts + c_l * 68 + k_l) = pk.u;
    }
    __syncthreads();
    const int c = t >> 2;
    const int seg = t & 3;
    const __hip_bfloat16* src = Ts + c * 68 + seg * 16;
    union { uint2 d[2]; uint4 qv; } o0, o1;
    o0.d[0] = *(const uint2*)(src + 0);
    o0.d[1] = *(const uint2*)(src + 4);
    o1.d[0] = *(const uint2*)(src + 8);
    o1.d[1] = *(const uint2*)(src + 12);
    __hip_bfloat16* dst = At + (size_t)(c0 + c) * K_DIM + k0 + seg * 16;
    *(uint4*)(dst + 0) = o0.qv;
    *(uint4*)(dst + 8) = o1.qv;
  } else {  // ---- cvt query -> qb (1024 blocks, grid-stride)
    if (b == 2048 && t == 0) wsf[4] = 0.0f;
    const int n4 = B_DIM * C_DIM / 4;
    int tid = (b - 2048) * 256 + t;
    for (int i = tid; i < n4; i += 1024 * 256) {
      float4 v = ((const float4*)q)[i];
      __hip_bfloat16 o[4] = {__float2bfloat16(v.x), __float2bfloat16(v.y),
                             __float2bfloat16(v.z), __float2bfloat16(v.w)};
      *(uint2*)(qb + 4 * (size_t)i) = *(const uint2*)o;
    }
  }
}

// --------------------------- gemm_m: P[z] = At @ At^T (K-chunk z) ---------
// Triangle-only (tm>=tn): 136 tiles x SPLITK=4 = 544 blocks, XCD-chunked
// (sw = (bid&7)*68 + bid>>3; 544 = 8*68 exact, bijective). m97 structure:
// 128x128 tile, 4 waves, single-buffer 32 KiB LDS, 2-barrier loop (fine at
// ~2.1 blocks/CU: cross-block overlap hides the barrier drain).
// Epilogue writes the tile and, for off-diagonal tiles, the float4 mirror.
__global__ __launch_bounds__(256, 4) void gemm_m(
    const __hip_bfloat16* __restrict__ At, float* __restrict__ P) {
  constexpr int BK = 64;
  constexpr int NT = KCHUNK / BK;  // 16
  __shared__ __align__(16) __hip_bfloat16 As[128 * BK];  // 16 KiB
  __shared__ __align__(16) __hip_bfloat16 Bs[128 * BK];  // 16 KiB
  const int bid = blockIdx.x;
  const int sw = (bid & 7) * 68 + (bid >> 3);
  const int z = sw / 136;
  const int bt = sw % 136;
  int r = (int)((sqrtf(8.0f * (float)bt + 1.0f) - 1.0f) * 0.5f);
  if ((r + 1) * (r + 2) / 2 <= bt) ++r;
  if (r * (r + 1) / 2 > bt) --r;
  const int tm_i = r;                       // [0,16)
  const int tn_i = bt - r * (r + 1) / 2;    // [0,tm_i]
  const int tid = threadIdx.x;
  const int wave = tid >> 6, lane = tid & 63;
  const int tile_m = tm_i * 128, tile_n = tn_i * 128;
  const int kstart = z * KCHUNK;
  const int wm = (wave >> 1) * 64, wn = (wave & 1) * 64;
  const int lr = lane >> 3, lcl = (lane & 7) ^ lr;
  const __hip_bfloat16* aB =
      At + (size_t)(tile_m + wave * 32 + lr) * K_DIM + kstart + lcl * 8;
  const __hip_bfloat16* bB =
      At + (size_t)(tile_n + wave * 32 + lr) * K_DIM + kstart + lcl * 8;
  const int l15 = lane & 15, lg = lane >> 4, l7 = lane & 7;
  f32x4 acc[4][4] = {};

  for (int t = 0; t < NT; ++t) {
#pragma unroll
    for (int c = 0; c < 4; ++c) {
      async_load16(aB + (size_t)(c * 8) * K_DIM + (size_t)t * BK,
                   &As[(wave * 32 + c * 8) * BK]);
      async_load16(bB + (size_t)(c * 8) * K_DIM + (size_t)t * BK,
                   &Bs[(wave * 32 + c * 8) * BK]);
    }
    __syncthreads();
#pragma unroll
    for (int kh = 0; kh < 2; ++kh) {
      bf16x8 a[4], bb[4];
#pragma unroll
      for (int f = 0; f < 4; ++f) {
        a[f]  = *(const bf16x8*)&As[(wm + f * 16 + l15) * BK +
                                    (((kh * 4 + lg) ^ l7) * 8)];
        bb[f] = *(const bf16x8*)&Bs[(wn + f * 16 + l15) * BK +
                                    (((kh * 4 + lg) ^ l7) * 8)];
      }
      __builtin_amdgcn_s_setprio(1);
#pragma unroll
      for (int f = 0; f < 4; ++f)
#pragma unroll
        for (int j = 0; j < 4; ++j)
          acc[f][j] = __builtin_amdgcn_mfma_f32_16x16x32_bf16(
              a[f], bb[j], acc[f][j], 0, 0, 0);
      __builtin_amdgcn_s_setprio(0);
    }
    __syncthreads();
  }

  // epilogue: fp32 partial + mirror. C/D: col = lane&15, row = (lane>>4)*4+reg
  float* Pz = P + (size_t)z * C_DIM * C_DIM;
  const bool mirror = (tm_i != tn_i);
#pragma unroll
  for (int f = 0; f < 4; ++f) {
    const int gm = tile_m + wm + f * 16 + lg * 4;
#pragma unroll
    for (int j = 0; j < 4; ++j) {
      const int gn = tile_n + wn + j * 16 + l15;
#pragma unroll
      for (int r2 = 0; r2 < 4; ++r2)
        Pz[(size_t)(gm + r2) * C_DIM + gn] = acc[f][j][r2];
      if (mirror) {
        f32x4 v = acc[f][j];
        *(f32x4*)&Pz[(size_t)gn * C_DIM + gm] = v;  // 16B aligned (gm%4==0)
      }
    }
  }
}

// ------------------- reduce4: Mb = bf16(sum P[z]) + trace -----------------
__global__ __launch_bounds__(256) void reduce4_kernel(
    const float* __restrict__ P, __hip_bfloat16* __restrict__ Mb,
    float* __restrict__ wsf) {
  const size_t CC = (size_t)C_DIM * C_DIM;
  const int n4 = (int)(CC / 4);
  int tid = blockIdx.x * blockDim.x + threadIdx.x;
  int stride = gridDim.x * blockDim.x;
  float tsum = 0.0f;
  bool hit = false;
  for (int i = tid; i < n4; i += stride) {
    float4 a = ((const float4*)P)[i];
#pragma unroll
    for (int z = 1; z < SPLITK; ++z) {
      float4 b = *(const float4*)(P + z * CC + (size_t)i * 4);
      a.x += b.x; a.y += b.y; a.z += b.z; a.w += b.w;
    }
    __hip_bfloat16 o[4] = {__float2bfloat16(a.x), __float2bfloat16(a.y),
                           __float2bfloat16(a.z), __float2bfloat16(a.w)};
    *(uint2*)(Mb + 4 * (size_t)i) = *(const uint2*)o;
    const int e0 = 4 * i;
    const int g = e0 >> 11;
    const int d = g * (C_DIM + 1);
    if (d >= e0 && d < e0 + 4) {
      const float av[4] = {a.x, a.y, a.z, a.w};
      tsum += av[d - e0];
      hit = true;
    }
  }
  if (hit) atomicAdd(wsf + 4, tsum);
}

// --------------------------- gemm_qm: out = c1 * qb @ Mb^T ----------------
// Single-barrier 4-phase schedule (see header). 256x256 tile, 8 waves
// (2Mx4N), wave tile 128x64, BK=64, double-buffered 128 KiB LDS.
// Grid 256, XCD-chunked (round-5 swizzle kept: FETCH -64% measured).
__global__ __launch_bounds__(512, 2) void gemm_qm(
    const __hip_bfloat16* __restrict__ Ab, const __hip_bfloat16* __restrict__ Bb,
    float* __restrict__ Fp, const float* __restrict__ ls,
    const float* __restrict__ wsf) {
  constexpr int BK = 64;
  constexpr int NT = C_DIM / BK;  // 32
  __shared__ __align__(16) __hip_bfloat16 As[2][256 * BK];
  __shared__ __align__(16) __hip_bfloat16 Bs[2][256 * BK];
  const int bid = blockIdx.x;
  const int sw = (bid & 7) * 32 + (bid >> 3);
  const int tn_i = sw & 7;    // [0,8)
  const int tm_i = sw >> 3;   // [0,32)
  const int tid = threadIdx.x;
  const int wave = tid >> 6, lane = tid & 63;
  const int tile_m = tm_i * 256, tile_n = tn_i * 256;
  const int wm = (wave >> 2) * 128, wn = (wave & 3) * 64;
  const int lr = lane >> 3, lcl = (lane & 7) ^ lr;
  const __hip_bfloat16* aBase =
      Ab + (size_t)(tile_m + wave * 16 + lr) * C_DIM + lcl * 8;
  const __hip_bfloat16* bBase =
      Bb + (size_t)(tile_n + wave * 16 + lr) * C_DIM + lcl * 8;
  const int l15 = lane & 15, lg = lane >> 4, l7 = lane & 7;

  auto stA = [&](int buf, int h, int t) {
    const __hip_bfloat16* s = aBase + (size_t)(h * 128) * C_DIM + (size_t)t * BK;
    __hip_bfloat16* d = &As[buf][(h * 128 + wave * 16) * BK];
    async_load16(s, d);
    async_load16(s + (size_t)8 * C_DIM, d + 8 * BK);
  };
  auto stB = [&](int buf, int h, int t) {
    const __hip_bfloat16* s = bBase + (size_t)(h * 128) * C_DIM + (size_t)t * BK;
    __hip_bfloat16* d = &Bs[buf][(h * 128 + wave * 16) * BK];
    async_load16(s, d);
    async_load16(s + (size_t)8 * C_DIM, d + 8 * BK);
  };

  f32x4 acc[8][4] = {};
  bf16x8 af[4], bfr[4];

  auto rdA = [&](int buf, int mh, int s) {
#pragma unroll
    for (int f = 0; f < 4; ++f)
      af[f] = *(const bf16x8*)&As[buf][(wm + mh * 64 + f * 16 + l15) * BK +
                                       (((s * 4 + lg) ^ l7) * 8)];
  };
  auto rdB = [&](int buf, int s) {
#pragma unroll
    for (int j = 0; j < 4; ++j)
      bfr[j] = *(const bf16x8*)&Bs[buf][(wn + j * 16 + l15) * BK +
                                        (((s * 4 + lg) ^ l7) * 8)];
  };
  auto mm = [&](int mh) {
    __builtin_amdgcn_s_setprio(1);
#pragma unroll
    for (int f = 0; f < 4; ++f)
#pragma unroll
      for (int j = 0; j < 4; ++j)
        acc[mh * 4 + f][j] = __builtin_amdgcn_mfma_f32_16x16x32_bf16(
            af[f], bfr[j], acc[mh * 4 + f][j], 0, 0, 0);
    __builtin_amdgcn_s_setprio(0);
  };

  // prologue: A(0),B(0) drained; B(1)'s 4 loads stay in flight
  stA(0, 0, 0); stA(0, 1, 0);
  stB(0, 0, 0); stB(0, 1, 0);
  stB(1, 0, 1); stB(1, 1, 1);
  VMCNT(4);
  SBAR;

  for (int t = 0; t < NT; ++t) {
    const int buf = t & 1;
    // ---- p0: (s0, mh0)
    rdA(buf, 0, 0);
    rdB(buf, 0);
    SBAR;
    if (t + 1 < NT) stA(buf ^ 1, 0, t + 1);
    LGKMCNT0;
    mm(0);
    // ---- p1: (s0, mh1)
    rdA(buf, 1, 0);
    SBAR;
    if (t + 1 < NT) stA(buf ^ 1, 1, t + 1);
    LGKMCNT0;
    mm(1);
    // ---- p2: (s1, mh0)
    rdA(buf, 0, 1);
    rdB(buf, 1);
    SBAR;
    LGKMCNT0;
    mm(0);
    // ---- p3: (s1, mh1)
    rdA(buf, 1, 1);
    VMCNT(0);  // drains A(t+1),B(t+1) (issued >=2 phases ago); cheap
    SBAR;
    if (t + 2 < NT) { stB(buf, 0, t + 2); stB(buf, 1, t + 2); }
    LGKMCNT0;
    mm(1);
  }

  // epilogue: C/D (16x16): col = lane&15, row = (lane>>4)*4 + reg
  const float c1 = 256.0f * fminf(expf(ls[0]), 5e-4f) / (wsf[4] + 1e-8f);
#pragma unroll
  for (int m = 0; m < 8; ++m) {
    const int gm = tile_m + wm + m * 16 + lg * 4;
#pragma unroll
    for (int j = 0; j < 4; ++j) {
      const int gn = tile_n + wn + j * 16 + l15;
#pragma unroll
      for (int r = 0; r < 4; ++r)
        Fp[(size_t)(gm + r) * C_DIM + gn] = c1 * acc[m][j][r];
    }
  }
}

// ------------------------------------------------------------- launch -----
extern "C" void kernel_launch(void* const* d_in, const int* in_sizes, int n_in,
                              void* d_out, int out_size, void* d_ws, size_t ws_size,
                              hipStream_t stream) {
  const float* query = (const float*)d_in[0];
  const float* A = (const float*)d_in[1];
  const float* ls = (const float*)d_in[2];
  float* out = (float*)d_out;

  char* ws = (char*)d_ws;
  float* wsf = (float*)ws;
  size_t off = 256;
  __hip_bfloat16* At = (__hip_bfloat16*)(ws + off);
  off += (size_t)C_DIM * K_DIM * 2;  // 16 MiB
  __hip_bfloat16* qb = (__hip_bfloat16*)(ws + off);
  off += (size_t)B_DIM * C_DIM * 2;  // 32 MiB
  __hip_bfloat16* Mb = (__hip_bfloat16*)(ws + off);  // 8 MiB

  // split-K fp32 partials live in the OUT buffer (4 x 16 MiB = 64 MiB =
  // out_size exactly); gemm_qm overwrites out afterwards.
  float* P = out;

  // 1) At = A^T bf16 ; qb = bf16(query) ; wsf[4] = 0
  prep_kernel<<<3072, 256, 0, stream>>>(A, At, query, qb, wsf);
  // 2) P[z] = At @ At^T, triangle-only (544 blocks, XCD-chunked)
  gemm_m<<<544, 256, 0, stream>>>(At, P);
  // 3) Mb = bf16(sum_z P[z]) + trace -> wsf[4]
  reduce4_kernel<<<1024, 256, 0, stream>>>(P, Mb, wsf);
  // 4) out = c1 * qb @ Mb^T  (single-barrier schedule; 256 blocks)
  gemm_qm<<<256, 512, 0, stream>>>(qb, Mb, out, ls, wsf);
}